// Round 14
// baseline (52604.755 us; speedup 1.0000x reference)
//
#include <hip/hip_runtime.h>
#include <hip/hip_bf16.h>
#include <stdint.h>

// ---------------- types ----------------
using bfrag_t = __attribute__((ext_vector_type(8))) short;   // 8 bf16 (4 VGPRs)
using f32x16  = __attribute__((ext_vector_type(16))) float;  // 32x32 MFMA acc

#define HID  512
#define H3   256
#define RB   128      // rows per block (two pipelined halves of 64)
#define NTH  512      // 8 waves
#define KSC  2.885390081777927f   // 2*log2(e): tanh(x) = 1 - 2/(exp2(KSC*x)+1)
// REGISTER CLIFF (R7/R9/R10/R12): 256 regs/wave at 2 waves/SIMD. Exceeding it
// spills to scratch in the K-loop -> FETCH explosion (10MB -> 17-30GB) and big
// regression. This half-pipelined design peaks at ~128 AGPR + ~60 VGPR.

static __device__ __forceinline__ uint32_t bf16_rne(float f) {
    uint32_t u = __float_as_uint(f);
    return (u + 0x7fffu + ((u >> 16) & 1u)) >> 16;
}
static __device__ __forceinline__ uint32_t pk_bf16(float a, float b) {
    union { __hip_bfloat162 h; uint32_t u; } c;
    c.h = __float22bfloat162_rn(make_float2(a, b));   // v_cvt_pk_bf16_f32 on gfx950
    return c.u;
}
static __device__ __forceinline__ float fast_exp2(float x) {
#if __has_builtin(__builtin_amdgcn_exp2f)
    return __builtin_amdgcn_exp2f(x);
#else
    return exp2f(x);
#endif
}
static __device__ __forceinline__ float fast_rcp(float x) {
#if __has_builtin(__builtin_amdgcn_rcpf)
    return __builtin_amdgcn_rcpf(x);
#else
    return 1.0f / x;
#endif
}
// input is PRE-SCALED by KSC (weights/biases scaled in prep)
static __device__ __forceinline__ float ftanh_s(float xs) {
    float e = fast_exp2(xs);
    return 1.0f - 2.0f * fast_rcp(e + 1.0f);
}
static __device__ __forceinline__ bfrag_t frag_of(uint4 v) {
    union { uint4 u; bfrag_t f; } c; c.u = v; return c.f;
}

// ---------------- prep: swizzle W2^T / W3^T (scaled) into 32x32x16 MFMA A-frag
// order; scaled W1-pack; scaled b2/b3; W4 per-lane pack for fused L3+L4 epi.
// A-frag (32x32x16 bf16): lane l -> m = l&31, k = kt*16 + (l>>5)*8 + j.
// W4 pack: t = [wu:3][lh:1][r:4][c:1]; m = wu*32 + (r&3) + 8*(r>>2) + 4*lh.
__global__ void prep_weights(const float* __restrict__ W1, const float* __restrict__ b1,
                             const float* __restrict__ W2, const float* __restrict__ b2,
                             const float* __restrict__ W3, const float* __restrict__ b3,
                             const float* __restrict__ W4,
                             uint4* __restrict__ o2, uint4* __restrict__ o3,
                             float* __restrict__ w1p, float* __restrict__ b2s,
                             float* __restrict__ b3s, float* __restrict__ w4f)
{
    int id = blockIdx.x * 256 + threadIdx.x;
    if (id < 32768) {                       // W2: 16 mt32 * 32 kt * 64 lanes
        int l = id & 63, kt = (id >> 6) & 31, mt = id >> 11;
        int m = mt * 32 + (l & 31), k0 = kt * 16 + (l >> 5) * 8;
        uint32_t p[4];
        #pragma unroll
        for (int jj = 0; jj < 4; ++jj) {
            float v0 = KSC * W2[(k0 + jj * 2    ) * 512 + m];  // W2^T[m][k] = W2[k][m]
            float v1 = KSC * W2[(k0 + jj * 2 + 1) * 512 + m];
            p[jj] = bf16_rne(v0) | (bf16_rne(v1) << 16);
        }
        o2[id] = make_uint4(p[0], p[1], p[2], p[3]);
    } else if (id < 49152) {                // W3: 8 mt32 * 32 kt * 64 lanes
        int id2 = id - 32768;
        int l = id2 & 63, kt = (id2 >> 6) & 31, mt = id2 >> 11;
        int m = mt * 32 + (l & 31), k0 = kt * 16 + (l >> 5) * 8;
        uint32_t p[4];
        #pragma unroll
        for (int jj = 0; jj < 4; ++jj) {
            float v0 = KSC * W3[(k0 + jj * 2    ) * 256 + m];
            float v1 = KSC * W3[(k0 + jj * 2 + 1) * 256 + m];
            p[jj] = bf16_rne(v0) | (bf16_rne(v1) << 16);
        }
        o3[id2] = make_uint4(p[0], p[1], p[2], p[3]);
    } else if (id < 49152 + 1536) {         // W1 pack: 64 chunks x 24 floats
        int t = id - 49152;
        int ck = t / 24, j = t % 24;
        int f = ck * 8 + (j & 7);
        float v = (j < 8) ? W1[f] : (j < 16) ? W1[512 + f] : b1[f];
        w1p[t] = KSC * v;
    } else if (id < 49152 + 1536 + 512) {
        int i = id - 49152 - 1536; b2s[i] = KSC * b2[i];
    } else if (id < 49152 + 1536 + 512 + 256) {
        int i = id - 49152 - 1536 - 512; b3s[i] = KSC * b3[i];
    } else if (id < 49152 + 1536 + 512 + 256 + 512) {
        int t = id - (49152 + 1536 + 512 + 256);    // 0..511
        int c  = t & 1;
        int r  = (t >> 1) & 15;
        int lh = (t >> 5) & 1;
        int wv = t >> 6;
        int m = wv * 32 + (r & 3) + 8 * (r >> 2) + 4 * lh;
        w4f[t] = W4[m * 2 + c];                     // NOT scaled (applied post-tanh)
    }
}

// ---------------- main persistent kernel ----------------
struct SmemT {
    uint4  hbuf[8192];       // 128 KB: [half][ck 0..63][row 0..63] (h1 then h2 in place)
    float  b2[HID];          // scaled
    float  b3[H3];           // scaled
    float  w4[512];          // per-lane W4 pack
    float  y [RB][2];
    float  z [RB][2];
    float  ya[RB][2];
    float  part[16][RB][2];  // fused L3+L4 partials: [wu*2+lh][row][c]
};                            // ~152 KB -> 1 block/CU

__global__ __launch_bounds__(NTH, 2) void node_kernel(
    const float* __restrict__ y0, const float* __restrict__ tp,
    const float* __restrict__ b4g,
    const uint4* __restrict__ w2A, const uint4* __restrict__ w3A,
    const float* __restrict__ w1p, const float* __restrict__ b2s,
    const float* __restrict__ b3s, const float* __restrict__ w4f,
    float* __restrict__ out, int Bn, int T)
{
    __shared__ SmemT s;
    const int tid = threadIdx.x;
    const int l   = tid & 63;
    const int w   = tid >> 6;                                  // wave 0..7
    const int wu  = __builtin_amdgcn_readfirstlane(w);         // provably uniform
    const int b0  = blockIdx.x * RB;
    const int ln  = l & 31, lh = l >> 5;

    for (int i = tid; i < HID; i += NTH) s.b2[i] = b2s[i];
    for (int i = tid; i < H3;  i += NTH) s.b3[i] = b3s[i];
    if (tid < 512) s.w4[tid] = w4f[tid];
    if (tid < RB) {
        float2 v = ((const float2*)y0)[b0 + tid];
        s.y [tid][0] = v.x; s.y [tid][1] = v.y;
        s.z [tid][0] = v.x; s.z [tid][1] = v.y;
        s.ya[tid][0] = v.x; s.ya[tid][1] = v.y;
        ((float2*)out)[b0 + tid] = v;          // trajectory[0] = y0
    }
    __syncthreads();

    const float* w1w = w1p + wu * 8 * 24;              // this wave's 8 chunks
    const uint4* pW2 = w2A + (wu * 64) * 64 + l;       // mt32 = wu*2 + mt
    const uint4* pW3 = w3A + (wu * 32) * 64 + l;       // mt32 = wu
    const float* w4l = &s.w4[(wu * 2 + lh) * 32];      // 16 (feat, c-pair) slots

    for (int st = 0; st < T - 1; ++st) {
        float dt = tp[st + 1] - tp[st];

        for (int e = 0; e < 4; ++e) {
            // prefetch L2's first A-frags (hide under P1)
            uint4 aC0 = pW2[0], aC1 = pW2[2048];
            uint4 aN0 = pW2[64], aN1 = pW2[2048 + 64];

            // ---- P1: L1(A) — rows 0..63, one row per lane ----
            {
                float za0 = s.z[l][0], za1 = s.z[l][1];
                #pragma unroll
                for (int i = 0; i < 8; ++i) {
                    const float* P = w1w + i * 24;   // uniform -> s_load
                    int ck = wu * 8 + i;
                    float xa[8];
                    #pragma unroll
                    for (int jj = 0; jj < 8; ++jj)
                        xa[jj] = ftanh_s(fmaf(za0, P[jj], fmaf(za1, P[8 + jj], P[16 + jj])));
                    s.hbuf[ck * 64 + l] = make_uint4(
                        pk_bf16(xa[0], xa[1]), pk_bf16(xa[2], xa[3]),
                        pk_bf16(xa[4], xa[5]), pk_bf16(xa[6], xa[7]));
                }
            }
            __syncthreads();

            // ---- P2: L1(B) interleaved with L2(A)-K  (M=512, N=64, K=512) ----
            f32x16 accA[2][2];
            #pragma unroll
            for (int mt = 0; mt < 2; ++mt) {
                int mb = (wu * 2 + mt) * 32 + 4 * lh;
                float bv[16];
                *(float4*)&bv[0]  = *(const float4*)&s.b2[mb];
                *(float4*)&bv[4]  = *(const float4*)&s.b2[mb + 8];
                *(float4*)&bv[8]  = *(const float4*)&s.b2[mb + 16];
                *(float4*)&bv[12] = *(const float4*)&s.b2[mb + 24];
                f32x16 a;
                #pragma unroll
                for (int r = 0; r < 16; ++r) a[r] = bv[r];
                accA[mt][0] = a; accA[mt][1] = a;
            }
            {
                float zb0 = s.z[64 + l][0], zb1 = s.z[64 + l][1];
                #pragma unroll
                for (int q = 0; q < 8; ++q) {
                    {   // one L1(B) chunk (VALU/trans) — overlaps matrix pipe
                        const float* P = w1w + q * 24;
                        int ck = wu * 8 + q;
                        float xb[8];
                        #pragma unroll
                        for (int jj = 0; jj < 8; ++jj)
                            xb[jj] = ftanh_s(fmaf(zb0, P[jj], fmaf(zb1, P[8 + jj], P[16 + jj])));
                        s.hbuf[4096 + ck * 64 + l] = make_uint4(
                            pk_bf16(xb[0], xb[1]), pk_bf16(xb[2], xb[3]),
                            pk_bf16(xb[4], xb[5]), pk_bf16(xb[6], xb[7]));
                    }
                    #pragma unroll
                    for (int k4 = 0; k4 < 4; ++k4) {
                        int kt = q * 4 + k4;
                        uint4 bF0 = s.hbuf[(kt * 2 + lh) * 64 + ln];
                        uint4 bF1 = s.hbuf[(kt * 2 + lh) * 64 + 32 + ln];
                        int kq = (kt < 30) ? (kt + 2) : 29;
                        uint4 aM0 = pW2[kq * 64];
                        uint4 aM1 = pW2[2048 + kq * 64];
                        accA[0][0] = __builtin_amdgcn_mfma_f32_32x32x16_bf16(
                            frag_of(aC0), frag_of(bF0), accA[0][0], 0, 0, 0);
                        accA[0][1] = __builtin_amdgcn_mfma_f32_32x32x16_bf16(
                            frag_of(aC0), frag_of(bF1), accA[0][1], 0, 0, 0);
                        accA[1][0] = __builtin_amdgcn_mfma_f32_32x32x16_bf16(
                            frag_of(aC1), frag_of(bF0), accA[1][0], 0, 0, 0);
                        accA[1][1] = __builtin_amdgcn_mfma_f32_32x32x16_bf16(
                            frag_of(aC1), frag_of(bF1), accA[1][1], 0, 0, 0);
                        aC0 = aN0; aC1 = aN1; aN0 = aM0; aN1 = aM1;
                    }
                }
            }
            // re-prime A-frags for L2(B) (same addresses, cache-hot)
            aC0 = pW2[0]; aC1 = pW2[2048];
            aN0 = pW2[64]; aN1 = pW2[2048 + 64];
            __syncthreads();   // h1A consumed; h1B ready

            // ---- P3: L2(A)-epi (h2A) interleaved with L2(B)-K ----
            f32x16 accB[2][2];
            #pragma unroll
            for (int mt = 0; mt < 2; ++mt) {
                int mb = (wu * 2 + mt) * 32 + 4 * lh;
                float bv[16];
                *(float4*)&bv[0]  = *(const float4*)&s.b2[mb];
                *(float4*)&bv[4]  = *(const float4*)&s.b2[mb + 8];
                *(float4*)&bv[8]  = *(const float4*)&s.b2[mb + 16];
                *(float4*)&bv[12] = *(const float4*)&s.b2[mb + 24];
                f32x16 a;
                #pragma unroll
                for (int r = 0; r < 16; ++r) a[r] = bv[r];
                accB[mt][0] = a; accB[mt][1] = a;
            }
            #pragma unroll
            for (int q4 = 0; q4 < 4; ++q4) {
                int emt = q4 >> 1, ent = q4 & 1;
                {   // epi slice of accA[emt][ent] -> bufA (h2A)
                    int m0 = (wu * 2 + emt) * 32 + 4 * lh;
                    int n  = ent * 32 + ln;
                    f32x16 c = accA[emt][ent];
                    #pragma unroll
                    for (int g = 0; g < 4; ++g) {
                        int ck = (m0 + 8 * g) >> 3;
                        uint32_t u0 = pk_bf16(ftanh_s(c[4 * g    ]), ftanh_s(c[4 * g + 1]));
                        uint32_t u1 = pk_bf16(ftanh_s(c[4 * g + 2]), ftanh_s(c[4 * g + 3]));
                        ((uint2*)s.hbuf)[((ck * 64 + n) << 1) | lh] = make_uint2(u0, u1);
                    }
                }
                #pragma unroll
                for (int k8 = 0; k8 < 8; ++k8) {
                    int kt = q4 * 8 + k8;
                    uint4 bF0 = s.hbuf[4096 + (kt * 2 + lh) * 64 + ln];
                    uint4 bF1 = s.hbuf[4096 + (kt * 2 + lh) * 64 + 32 + ln];
                    int kq = (kt < 30) ? (kt + 2) : 29;
                    uint4 aM0 = pW2[kq * 64];
                    uint4 aM1 = pW2[2048 + kq * 64];
                    accB[0][0] = __builtin_amdgcn_mfma_f32_32x32x16_bf16(
                        frag_of(aC0), frag_of(bF0), accB[0][0], 0, 0, 0);
                    accB[0][1] = __builtin_amdgcn_mfma_f32_32x32x16_bf16(
                        frag_of(aC0), frag_of(bF1), accB[0][1], 0, 0, 0);
                    accB[1][0] = __builtin_amdgcn_mfma_f32_32x32x16_bf16(
                        frag_of(aC1), frag_of(bF0), accB[1][0], 0, 0, 0);
                    accB[1][1] = __builtin_amdgcn_mfma_f32_32x32x16_bf16(
                        frag_of(aC1), frag_of(bF1), accB[1][1], 0, 0, 0);
                    aC0 = aN0; aC1 = aN1; aN0 = aM0; aN1 = aM1;
                }
            }
            uint4 c3C = pW3[0], c3N = pW3[64];   // L3(A) A-frags
            __syncthreads();   // h2A ready; h1B consumed

            // ---- P4: L2(B)-epi (h2B) interleaved with L3(A)-K (M=256,N=64) ----
            f32x16 acc3A[2];
            {
                int mb = wu * 32 + 4 * lh;
                float bv[16];
                *(float4*)&bv[0]  = *(const float4*)&s.b3[mb];
                *(float4*)&bv[4]  = *(const float4*)&s.b3[mb + 8];
                *(float4*)&bv[8]  = *(const float4*)&s.b3[mb + 16];
                *(float4*)&bv[12] = *(const float4*)&s.b3[mb + 24];
                f32x16 a;
                #pragma unroll
                for (int r = 0; r < 16; ++r) a[r] = bv[r];
                acc3A[0] = a; acc3A[1] = a;
            }
            #pragma unroll
            for (int q4 = 0; q4 < 4; ++q4) {
                int emt = q4 >> 1, ent = q4 & 1;
                {   // epi slice of accB[emt][ent] -> bufB (h2B)
                    int m0 = (wu * 2 + emt) * 32 + 4 * lh;
                    int n  = ent * 32 + ln;
                    f32x16 c = accB[emt][ent];
                    #pragma unroll
                    for (int g = 0; g < 4; ++g) {
                        int ck = (m0 + 8 * g) >> 3;
                        uint32_t u0 = pk_bf16(ftanh_s(c[4 * g    ]), ftanh_s(c[4 * g + 1]));
                        uint32_t u1 = pk_bf16(ftanh_s(c[4 * g + 2]), ftanh_s(c[4 * g + 3]));
                        ((uint2*)s.hbuf)[((4096 + ck * 64 + n) << 1) | lh] = make_uint2(u0, u1);
                    }
                }
                #pragma unroll
                for (int k8 = 0; k8 < 8; ++k8) {
                    int kt = q4 * 8 + k8;
                    uint4 bF0 = s.hbuf[(kt * 2 + lh) * 64 + ln];          // h2A
                    uint4 bF1 = s.hbuf[(kt * 2 + lh) * 64 + 32 + ln];
                    int kq = (kt < 30) ? (kt + 2) : 29;
                    uint4 aM = pW3[kq * 64];
                    acc3A[0] = __builtin_amdgcn_mfma_f32_32x32x16_bf16(
                        frag_of(c3C), frag_of(bF0), acc3A[0], 0, 0, 0);
                    acc3A[1] = __builtin_amdgcn_mfma_f32_32x32x16_bf16(
                        frag_of(c3C), frag_of(bF1), acc3A[1], 0, 0, 0);
                    c3C = c3N; c3N = aM;
                }
            }
            c3C = pW3[0]; c3N = pW3[64];   // re-prime for L3(B)
            __syncthreads();   // h2B ready; h2A consumed

            // ---- P5: L3(A)-fused-epi+L4(A) interleaved with L3(B)-K;
            //          then L3(B)-fused-epi+L4(B) (same-wave, no barrier) ----
            f32x16 acc3B[2];
            {
                int mb = wu * 32 + 4 * lh;
                float bv[16];
                *(float4*)&bv[0]  = *(const float4*)&s.b3[mb];
                *(float4*)&bv[4]  = *(const float4*)&s.b3[mb + 8];
                *(float4*)&bv[8]  = *(const float4*)&s.b3[mb + 16];
                *(float4*)&bv[12] = *(const float4*)&s.b3[mb + 24];
                f32x16 a;
                #pragma unroll
                for (int r = 0; r < 16; ++r) a[r] = bv[r];
                acc3B[0] = a; acc3B[1] = a;
            }
            #pragma unroll
            for (int h2 = 0; h2 < 2; ++h2) {
                {   // fused epi: tanh(acc3A[h2]) dotted with per-lane W4 slice
                    float p0 = 0.f, p1 = 0.f;
                    #pragma unroll
                    for (int r = 0; r < 16; ++r) {
                        float hh = ftanh_s(acc3A[h2][r]);
                        p0 = fmaf(hh, w4l[r * 2],     p0);
                        p1 = fmaf(hh, w4l[r * 2 + 1], p1);
                    }
                    s.part[wu * 2 + lh][h2 * 32 + ln][0] = p0;
                    s.part[wu * 2 + lh][h2 * 32 + ln][1] = p1;
                }
                #pragma unroll
                for (int k16 = 0; k16 < 16; ++k16) {
                    int kt = h2 * 16 + k16;
                    uint4 bF0 = s.hbuf[4096 + (kt * 2 + lh) * 64 + ln];   // h2B
                    uint4 bF1 = s.hbuf[4096 + (kt * 2 + lh) * 64 + 32 + ln];
                    int kq = (kt < 30) ? (kt + 2) : 29;
                    uint4 aM = pW3[kq * 64];
                    acc3B[0] = __builtin_amdgcn_mfma_f32_32x32x16_bf16(
                        frag_of(c3C), frag_of(bF0), acc3B[0], 0, 0, 0);
                    acc3B[1] = __builtin_amdgcn_mfma_f32_32x32x16_bf16(
                        frag_of(c3C), frag_of(bF1), acc3B[1], 0, 0, 0);
                    c3C = c3N; c3N = aM;
                }
            }
            #pragma unroll
            for (int nt = 0; nt < 2; ++nt) {   // L3(B)+L4(B), own-wave data only
                float p0 = 0.f, p1 = 0.f;
                #pragma unroll
                for (int r = 0; r < 16; ++r) {
                    float hh = ftanh_s(acc3B[nt][r]);
                    p0 = fmaf(hh, w4l[r * 2],     p0);
                    p1 = fmaf(hh, w4l[r * 2 + 1], p1);
                }
                s.part[wu * 2 + lh][64 + nt * 32 + ln][0] = p0;
                s.part[wu * 2 + lh][64 + nt * 32 + ln][1] = p1;
            }
            __syncthreads();   // all partials ready; h2B consumed

            // ---- P6: reduce partials + RK4 combine ----
            if (tid < RB) {
                float k0 = b4g[0], k1 = b4g[1];
                #pragma unroll
                for (int p = 0; p < 16; ++p) {
                    k0 += s.part[p][tid][0];
                    k1 += s.part[p][tid][1];
                }
                float wg = (e == 0 || e == 3) ? dt * (1.f / 6.f) : dt * (1.f / 3.f);
                float ya0 = s.ya[tid][0] + wg * k0;
                float ya1 = s.ya[tid][1] + wg * k1;
                s.ya[tid][0] = ya0; s.ya[tid][1] = ya1;
                if (e < 3) {
                    float aa = (e == 2) ? dt : dt * 0.5f;
                    s.z[tid][0] = s.y[tid][0] + aa * k0;
                    s.z[tid][1] = s.y[tid][1] + aa * k1;
                } else {
                    s.y[tid][0] = ya0; s.y[tid][1] = ya1;
                    s.z[tid][0] = ya0; s.z[tid][1] = ya1;
                    ((float2*)out)[(size_t)(st + 1) * Bn + b0 + tid] =
                        make_float2(ya0, ya1);
                }
            }
            __syncthreads();
        }
    }
}

extern "C" void kernel_launch(void* const* d_in, const int* in_sizes, int n_in,
                              void* d_out, int out_size, void* d_ws, size_t ws_size,
                              hipStream_t stream)
{
    const float* y0 = (const float*)d_in[0];
    const float* tp = (const float*)d_in[1];
    const float* W1 = (const float*)d_in[2];
    const float* b1 = (const float*)d_in[3];
    const float* W2 = (const float*)d_in[4];
    const float* b2 = (const float*)d_in[5];
    const float* W3 = (const float*)d_in[6];
    const float* b3 = (const float*)d_in[7];
    const float* W4 = (const float*)d_in[8];
    const float* b4 = (const float*)d_in[9];
    float* out = (float*)d_out;

    const int Bn = in_sizes[0] / 2;
    const int T  = in_sizes[1];

    uint4* w2A = (uint4*)d_ws;            // 32768 uint4 = 512 KB
    uint4* w3A = w2A + 32768;             // 16384 uint4 = 256 KB
    float* w1p = (float*)(w3A + 16384);   // 1536 floats (scaled W1 pack)
    float* b2s = w1p + 1536;              // 512 floats
    float* b3s = b2s + 512;               // 256 floats
    float* w4f = b3s + 256;               // 512 floats (per-lane W4 pack)

    prep_weights<<<204, 256, 0, stream>>>(W1, b1, W2, b2, W3, b3, W4,
                                          w2A, w3A, w1p, b2s, b3s, w4f);
    node_kernel<<<Bn / RB, NTH, 0, stream>>>(y0, tp, b4,
                                             w2A, w3A, w1p, b2s, b3s, w4f,
                                             out, Bn, T);
}

// Round 16
// 29253.711 us; speedup vs baseline: 1.7982x; 1.7982x over previous
//
#include <hip/hip_runtime.h>
#include <hip/hip_bf16.h>
#include <stdint.h>

// ---------------- types ----------------
using bfrag_t = __attribute__((ext_vector_type(8))) short;   // 8 bf16 (4 VGPRs)
using f32x16  = __attribute__((ext_vector_type(16))) float;  // 32x32 MFMA acc

#define HID  512
#define H3   256
#define RB   64       // 72.5KB LDS -> 2 blocks/CU co-resident (cross-block pipe overlap)
#define NTH  512      // 8 waves
#define KSC  2.885390081777927f   // 2*log2(e): tanh(x) = 1 - 2/(exp2(KSC*x)+1)
// REGISTER CLIFF (R7/R9/R10/R12/R14): budget = 512 regs/SIMD / waves-per-SIMD.
// At 4 waves/SIMD the cap is 128/wave. R7 sat at exactly 64 AGPR + 64 VGPR = 128
// and spilled (WRITE 610MB vs 256 baseline). This version deletes the prefetch
// rotation (-16 VGPR) and unroll pragma to land ~110 < 128. TLP (4 waves/SIMD)
// replaces the prefetch for latency hiding.

static __device__ __forceinline__ uint32_t bf16_rne(float f) {
    uint32_t u = __float_as_uint(f);
    return (u + 0x7fffu + ((u >> 16) & 1u)) >> 16;
}
static __device__ __forceinline__ uint32_t pk_bf16(float a, float b) {
    union { __hip_bfloat162 h; uint32_t u; } c;
    c.h = __float22bfloat162_rn(make_float2(a, b));   // v_cvt_pk_bf16_f32 on gfx950
    return c.u;
}
static __device__ __forceinline__ float fast_exp2(float x) {
#if __has_builtin(__builtin_amdgcn_exp2f)
    return __builtin_amdgcn_exp2f(x);
#else
    return exp2f(x);
#endif
}
static __device__ __forceinline__ float fast_rcp(float x) {
#if __has_builtin(__builtin_amdgcn_rcpf)
    return __builtin_amdgcn_rcpf(x);
#else
    return 1.0f / x;
#endif
}
// input is PRE-SCALED by KSC (weights/biases scaled in prep)
static __device__ __forceinline__ float ftanh_s(float xs) {
    float e = fast_exp2(xs);
    return 1.0f - 2.0f * fast_rcp(e + 1.0f);
}
static __device__ __forceinline__ bfrag_t frag_of(uint4 v) {
    union { uint4 u; bfrag_t f; } c; c.u = v; return c.f;
}

// ---------------- prep: swizzle W2^T / W3^T (scaled by KSC) into 32x32x16 MFMA
// A-frag order; also emit scaled W1-pack [ck][w0*8|w1*8|b*8] and scaled b2/b3. ----
// A-frag layout (32x32x16 bf16): lane l -> m = l&31, k = kt*16 + (l>>5)*8 + j (j=0..7,
// packed as 4 dwords of (even,odd) bf16 pairs). Index: [(mt32*32 + kt)*64 + l].
__global__ void prep_weights(const float* __restrict__ W1, const float* __restrict__ b1,
                             const float* __restrict__ W2, const float* __restrict__ b2,
                             const float* __restrict__ W3, const float* __restrict__ b3,
                             uint4* __restrict__ o2, uint4* __restrict__ o3,
                             float* __restrict__ w1p, float* __restrict__ b2s,
                             float* __restrict__ b3s)
{
    int id = blockIdx.x * 256 + threadIdx.x;
    if (id < 32768) {                       // W2: 16 mt32 * 32 kt * 64 lanes
        int l = id & 63, kt = (id >> 6) & 31, mt = id >> 11;
        int m = mt * 32 + (l & 31), k0 = kt * 16 + (l >> 5) * 8;
        uint32_t p[4];
        #pragma unroll
        for (int jj = 0; jj < 4; ++jj) {
            float v0 = KSC * W2[(k0 + jj * 2    ) * 512 + m];  // W2^T[m][k] = W2[k][m]
            float v1 = KSC * W2[(k0 + jj * 2 + 1) * 512 + m];
            p[jj] = bf16_rne(v0) | (bf16_rne(v1) << 16);
        }
        o2[id] = make_uint4(p[0], p[1], p[2], p[3]);
    } else if (id < 49152) {                // W3: 8 mt32 * 32 kt * 64 lanes
        int id2 = id - 32768;
        int l = id2 & 63, kt = (id2 >> 6) & 31, mt = id2 >> 11;
        int m = mt * 32 + (l & 31), k0 = kt * 16 + (l >> 5) * 8;
        uint32_t p[4];
        #pragma unroll
        for (int jj = 0; jj < 4; ++jj) {
            float v0 = KSC * W3[(k0 + jj * 2    ) * 256 + m];
            float v1 = KSC * W3[(k0 + jj * 2 + 1) * 256 + m];
            p[jj] = bf16_rne(v0) | (bf16_rne(v1) << 16);
        }
        o3[id2] = make_uint4(p[0], p[1], p[2], p[3]);
    } else if (id < 49152 + 1536) {         // W1 pack: 64 chunks x 24 floats
        int t = id - 49152;
        int ck = t / 24, j = t % 24;
        int f = ck * 8 + (j & 7);
        float v = (j < 8) ? W1[f] : (j < 16) ? W1[512 + f] : b1[f];
        w1p[t] = KSC * v;
    } else if (id < 49152 + 1536 + 512) {
        int i = id - 49152 - 1536; b2s[i] = KSC * b2[i];
    } else if (id < 49152 + 1536 + 512 + 256) {
        int i = id - 49152 - 1536 - 512; b3s[i] = KSC * b3[i];
    }
}

// ---------------- main persistent kernel ----------------
struct SmemT {
    uint4  hbuf[64 * RB];    // 64 KB: h1/h2 (512 feats) or h3 (first 32 chunks)
    float  b2[HID];          // scaled
    float  b3[H3];           // scaled
    float  y [RB][2];
    float  z [RB][2];
    float  ya[RB][2];
    float  part[8][RB][2];   // layer4 partials (one per wave)
};                            // ~72.5 KB -> 2 blocks/CU

__global__ __launch_bounds__(NTH, 4) void node_kernel(
    const float* __restrict__ y0, const float* __restrict__ tp,
    const float* __restrict__ W4g, const float* __restrict__ b4g,
    const uint4* __restrict__ w2A, const uint4* __restrict__ w3A,
    const float* __restrict__ w1p, const float* __restrict__ b2s,
    const float* __restrict__ b3s,
    float* __restrict__ out, int Bn, int T)
{
    __shared__ SmemT s;
    const int tid = threadIdx.x;
    const int l   = tid & 63;
    const int w   = tid >> 6;                                  // wave 0..7
    const int wu  = __builtin_amdgcn_readfirstlane(w);         // provably uniform
    const int b0  = blockIdx.x * RB;
    const int ln  = l & 31, lh = l >> 5;

    // stage biases (scaled) to LDS; init y/z/ya; write trajectory[0]
    for (int i = tid; i < HID; i += NTH) s.b2[i] = b2s[i];
    for (int i = tid; i < H3;  i += NTH) s.b3[i] = b3s[i];
    if (tid < RB) {
        float2 v = ((const float2*)y0)[b0 + tid];
        s.y [tid][0] = v.x; s.y [tid][1] = v.y;
        s.z [tid][0] = v.x; s.z [tid][1] = v.y;
        s.ya[tid][0] = v.x; s.ya[tid][1] = v.y;
        ((float2*)out)[b0 + tid] = v;          // trajectory[0] = y0
    }
    __syncthreads();

    const float* w1w = w1p + wu * 8 * 24;      // this wave's 8 chunks (uniform)
    // per-wave weight base pointers: tile (mt,kt) at pW2[mt*2048 + kt*64]
    const uint4* pW2 = w2A + (wu * 64) * 64 + l;       // mt32 = wu*2 + mt
    const uint4* pW3 = w3A + (wu * 32) * 64 + l;       // mt32 = wu (single m-tile)

    for (int st = 0; st < T - 1; ++st) {
        float dt = tp[st + 1] - tp[st];

        for (int e = 0; e < 4; ++e) {
            // ---- layer1: h1 = tanh(z @ W1 + b1); one row per lane ----
            {
                float zl0 = s.z[l][0], zl1 = s.z[l][1];
                #pragma unroll
                for (int i = 0; i < 8; ++i) {
                    const float* P = w1w + i * 24;   // uniform -> s_load
                    int ck = wu * 8 + i;
                    float xa[8];
                    #pragma unroll
                    for (int jj = 0; jj < 8; ++jj) {
                        float wa = P[jj], wb = P[8 + jj], bb = P[16 + jj];
                        xa[jj] = ftanh_s(fmaf(zl0, wa, fmaf(zl1, wb, bb)));
                    }
                    s.hbuf[ck * RB + l] = make_uint4(
                        pk_bf16(xa[0], xa[1]), pk_bf16(xa[2], xa[3]),
                        pk_bf16(xa[4], xa[5]), pk_bf16(xa[6], xa[7]));
                }
            }
            __syncthreads();

            // ---- layer2: h2^T = W2^T @ h1^T + b2   M=512, N=64, K=512 (32x32x16)
            //      no register prefetch: TLP (4 waves/SIMD) hides A-frag latency ----
            {
                f32x16 acc[2][2];
                #pragma unroll
                for (int mt = 0; mt < 2; ++mt) {
                    int mb = (wu * 2 + mt) * 32 + 4 * lh;
                    float bv[16];
                    *(float4*)&bv[0]  = *(const float4*)&s.b2[mb];
                    *(float4*)&bv[4]  = *(const float4*)&s.b2[mb + 8];
                    *(float4*)&bv[8]  = *(const float4*)&s.b2[mb + 16];
                    *(float4*)&bv[12] = *(const float4*)&s.b2[mb + 24];
                    f32x16 a;
                    #pragma unroll
                    for (int r = 0; r < 16; ++r) a[r] = bv[r];
                    acc[mt][0] = a; acc[mt][1] = a;
                }
                for (int kt = 0; kt < 32; ++kt) {
                    uint4 aA0 = pW2[kt * 64];
                    uint4 aA1 = pW2[2048 + kt * 64];
                    uint4 bF0 = s.hbuf[(kt * 2 + lh) * RB + ln];
                    uint4 bF1 = s.hbuf[(kt * 2 + lh) * RB + 32 + ln];
                    acc[0][0] = __builtin_amdgcn_mfma_f32_32x32x16_bf16(
                        frag_of(aA0), frag_of(bF0), acc[0][0], 0, 0, 0);
                    acc[0][1] = __builtin_amdgcn_mfma_f32_32x32x16_bf16(
                        frag_of(aA0), frag_of(bF1), acc[0][1], 0, 0, 0);
                    acc[1][0] = __builtin_amdgcn_mfma_f32_32x32x16_bf16(
                        frag_of(aA1), frag_of(bF0), acc[1][0], 0, 0, 0);
                    acc[1][1] = __builtin_amdgcn_mfma_f32_32x32x16_bf16(
                        frag_of(aA1), frag_of(bF1), acc[1][1], 0, 0, 0);
                }
                __syncthreads();   // all waves done reading h1
                // epilogue: tanh (pre-scaled), pack, overwrite hbuf with h2
                // C/D: col = ln (batch row), row = (r&3) + 8*(r>>2) + 4*lh
                #pragma unroll
                for (int mt = 0; mt < 2; ++mt) {
                    int m0 = (wu * 2 + mt) * 32 + 4 * lh;
                    int hi = lh;                     // (m0>>2)&1
                    #pragma unroll
                    for (int nt = 0; nt < 2; ++nt) {
                        int n = nt * 32 + ln;
                        f32x16 c = acc[mt][nt];
                        #pragma unroll
                        for (int g = 0; g < 4; ++g) {
                            int ck = (m0 + 8 * g) >> 3;
                            uint32_t u0 = pk_bf16(ftanh_s(c[4 * g    ]), ftanh_s(c[4 * g + 1]));
                            uint32_t u1 = pk_bf16(ftanh_s(c[4 * g + 2]), ftanh_s(c[4 * g + 3]));
                            ((uint2*)s.hbuf)[((ck * RB + n) << 1) | hi] = make_uint2(u0, u1);
                        }
                    }
                }
                __syncthreads();
            }

            // ---- layer3: h3^T = W3^T @ h2^T + b3   M=256, N=64, K=512 (32x32x16) ----
            {
                f32x16 acc3[2];
                {
                    int mb = wu * 32 + 4 * lh;
                    float bv[16];
                    *(float4*)&bv[0]  = *(const float4*)&s.b3[mb];
                    *(float4*)&bv[4]  = *(const float4*)&s.b3[mb + 8];
                    *(float4*)&bv[8]  = *(const float4*)&s.b3[mb + 16];
                    *(float4*)&bv[12] = *(const float4*)&s.b3[mb + 24];
                    f32x16 a;
                    #pragma unroll
                    for (int r = 0; r < 16; ++r) a[r] = bv[r];
                    acc3[0] = a; acc3[1] = a;
                }
                for (int kt = 0; kt < 32; ++kt) {
                    uint4 aA = pW3[kt * 64];
                    uint4 bF0 = s.hbuf[(kt * 2 + lh) * RB + ln];
                    uint4 bF1 = s.hbuf[(kt * 2 + lh) * RB + 32 + ln];
                    acc3[0] = __builtin_amdgcn_mfma_f32_32x32x16_bf16(
                        frag_of(aA), frag_of(bF0), acc3[0], 0, 0, 0);
                    acc3[1] = __builtin_amdgcn_mfma_f32_32x32x16_bf16(
                        frag_of(aA), frag_of(bF1), acc3[1], 0, 0, 0);
                }
                __syncthreads();   // all waves done reading h2
                {
                    int m0 = wu * 32 + 4 * lh;   // feature 0..255 -> ck 0..31
                    int hi = lh;
                    #pragma unroll
                    for (int nt = 0; nt < 2; ++nt) {
                        int n = nt * 32 + ln;
                        f32x16 c = acc3[nt];
                        #pragma unroll
                        for (int g = 0; g < 4; ++g) {
                            int ck = (m0 + 8 * g) >> 3;
                            uint32_t u0 = pk_bf16(ftanh_s(c[4 * g    ]), ftanh_s(c[4 * g + 1]));
                            uint32_t u1 = pk_bf16(ftanh_s(c[4 * g + 2]), ftanh_s(c[4 * g + 3]));
                            ((uint2*)s.hbuf)[((ck * RB + n) << 1) | hi] = make_uint2(u0, u1);
                        }
                    }
                }
                __syncthreads();
            }

            // ---- layer4 partials: contiguous-row reads, uniform W4 s_loads ----
            {
                int r  = l;                                          // 64 rows
                int qq = wu;                                         // wave -> 4 chunks
                float a0 = 0.f, a1 = 0.f;
                #pragma unroll
                for (int j = 0; j < 4; ++j) {
                    int ck = qq * 4 + j;
                    uint4 hv = s.hbuf[ck * RB + r];
                    const uint32_t* pu = (const uint32_t*)&hv;
                    #pragma unroll
                    for (int jj = 0; jj < 4; ++jj) {
                        uint32_t uu = pu[jj];
                        float h0 = __uint_as_float(uu << 16);
                        float h1 = __uint_as_float(uu & 0xffff0000u);
                        int f = ck * 8 + jj * 2;                     // uniform
                        a0 = fmaf(h0, W4g[f * 2],     fmaf(h1, W4g[f * 2 + 2], a0));
                        a1 = fmaf(h0, W4g[f * 2 + 1], fmaf(h1, W4g[f * 2 + 3], a1));
                    }
                }
                s.part[qq][r][0] = a0; s.part[qq][r][1] = a1;
            }
            __syncthreads();

            // ---- reduce partials + RK4 combine (also seeds next stage's z/ya) ----
            if (tid < RB) {
                float k0 = b4g[0], k1 = b4g[1];
                #pragma unroll
                for (int p = 0; p < 8; ++p) {
                    k0 += s.part[p][tid][0];
                    k1 += s.part[p][tid][1];
                }
                float wg = (e == 0 || e == 3) ? dt * (1.f / 6.f) : dt * (1.f / 3.f);
                float ya0 = s.ya[tid][0] + wg * k0;
                float ya1 = s.ya[tid][1] + wg * k1;
                s.ya[tid][0] = ya0; s.ya[tid][1] = ya1;
                if (e < 3) {
                    float aa = (e == 2) ? dt : dt * 0.5f;
                    s.z[tid][0] = s.y[tid][0] + aa * k0;
                    s.z[tid][1] = s.y[tid][1] + aa * k1;
                } else {
                    s.y[tid][0] = ya0; s.y[tid][1] = ya1;
                    s.z[tid][0] = ya0; s.z[tid][1] = ya1;   // z/ya for next stage = y_next
                    ((float2*)out)[(size_t)(st + 1) * Bn + b0 + tid] =
                        make_float2(ya0, ya1);
                }
            }
            __syncthreads();
        }
    }
}

extern "C" void kernel_launch(void* const* d_in, const int* in_sizes, int n_in,
                              void* d_out, int out_size, void* d_ws, size_t ws_size,
                              hipStream_t stream)
{
    const float* y0 = (const float*)d_in[0];
    const float* tp = (const float*)d_in[1];
    const float* W1 = (const float*)d_in[2];
    const float* b1 = (const float*)d_in[3];
    const float* W2 = (const float*)d_in[4];
    const float* b2 = (const float*)d_in[5];
    const float* W3 = (const float*)d_in[6];
    const float* b3 = (const float*)d_in[7];
    const float* W4 = (const float*)d_in[8];
    const float* b4 = (const float*)d_in[9];
    float* out = (float*)d_out;

    const int Bn = in_sizes[0] / 2;
    const int T  = in_sizes[1];

    uint4* w2A = (uint4*)d_ws;            // 32768 uint4 = 512 KB
    uint4* w3A = w2A + 32768;             // 16384 uint4 = 256 KB
    float* w1p = (float*)(w3A + 16384);   // 1536 floats (scaled W1 pack)
    float* b2s = w1p + 1536;              // 512 floats
    float* b3s = b2s + 512;               // 256 floats

    prep_weights<<<201, 256, 0, stream>>>(W1, b1, W2, b2, W3, b3,
                                          w2A, w3A, w1p, b2s, b3s);
    node_kernel<<<Bn / RB, NTH, 0, stream>>>(y0, tp, W4, b4,
                                             w2A, w3A, w1p, b2s, b3s, out, Bn, T);
}